// Round 13
// baseline (234.197 us; speedup 1.0000x reference)
//
#include <hip/hip_runtime.h>
#include <hip/hip_bf16.h>

#define BI   4
#define LI   256
#define EI   768
#define DI   1536
#define NI   16
#define RI   48
#define KI   4
#define NDIRS 4
#define F2D  3072              // 2*D
#define MROWS 1024             // B*L
#define LOG2E 1.4426950408889634f

typedef float    floatx2 __attribute__((ext_vector_type(2)));
typedef float    floatx4 __attribute__((ext_vector_type(4)));
typedef _Float16 halfx2  __attribute__((ext_vector_type(2)));
typedef _Float16 halfx4  __attribute__((ext_vector_type(4)));
typedef _Float16 halfx8  __attribute__((ext_vector_type(8)));

typedef __attribute__((address_space(3))) unsigned lds_u32;
typedef __attribute__((address_space(1))) const unsigned glb_u32;

__device__ __forceinline__ void load16(const _Float16* g, _Float16* l) {
    __builtin_amdgcn_global_load_lds((glb_u32*)g, (lds_u32*)l, 16, 0, 0);
}

__device__ __forceinline__ int perm_idx(int dir, int j) {
    switch (dir) {
        case 0:  return j;
        case 1:  return 255 - j;
        case 2:  return ((j & 15) << 4) | (j >> 4);
        default: return 255 - (((j & 15) << 4) | (j >> 4));
    }
}

// DPP-based add of a permuted copy (VALU pipe, no LDS traffic).
template<int CTRL>
__device__ __forceinline__ float dpp_add(float p) {
    int t = __builtin_amdgcn_update_dpp(0, __builtin_bit_cast(int, p),
                                        CTRL, 0xf, 0xf, true);
    return p + __builtin_bit_cast(float, t);
}
// sum over 8 consecutive lanes (tid&7 group)
__device__ __forceinline__ float grp8_sum(float p) {
    p = dpp_add<0xB1>(p);    // quad_perm [1,0,3,2]  : xor 1
    p = dpp_add<0x4E>(p);    // quad_perm [2,3,0,1]  : xor 2
    p = dpp_add<0x141>(p);   // row_half_mirror      : combine quads
    return p;
}

// ---------------------------------------------------------------------------
// Tiled hi/lo-fp16 GEMM core. LDS tiles [rows][32] fp16, unpadded
// (global_load_lds lane-order). acc += ah*bh + ah*bl + al*bh.
// ---------------------------------------------------------------------------
template<int BM, int BN, int WGN, int FM, int FN>
__device__ __forceinline__ void gemm_core(const _Float16* __restrict__ Ah,
                                          const _Float16* __restrict__ Al, int lda,
                                          const _Float16* __restrict__ Bh,
                                          const _Float16* __restrict__ Bl, int ldb,
                                          int nChunks, _Float16* smem,
                                          floatx4 (&acc)[FM][FN]) {
    const int tid = threadIdx.x, lane = tid & 63, wave = tid >> 6;
    const int wave_m = wave / WGN, wave_n = wave % WGN;
    _Float16* sAh = smem;
    _Float16* sAl = smem + BM * 32;
    _Float16* sBh = smem + BM * 64;
    _Float16* sBl = smem + BM * 64 + BN * 32;
    const int rr = lane & 15, koff = (lane >> 4) * 8;
    const int arow = wave_m * FM * 16, brow = wave_n * FN * 16;

    for (int c = 0; c < nChunks; ++c) {
        for (int idx = tid; idx < BM * 4; idx += 256) {
            int r = idx >> 2, s = (idx & 3) * 8;
            load16(Ah + (size_t)r * lda + c * 32 + s, sAh + idx * 8);
            load16(Al + (size_t)r * lda + c * 32 + s, sAl + idx * 8);
        }
        for (int idx = tid; idx < BN * 4; idx += 256) {
            int r = idx >> 2, s = (idx & 3) * 8;
            load16(Bh + (size_t)r * ldb + c * 32 + s, sBh + idx * 8);
            load16(Bl + (size_t)r * ldb + c * 32 + s, sBl + idx * 8);
        }
        asm volatile("s_waitcnt vmcnt(0)" ::: "memory");
        __syncthreads();

        halfx8 ahf[FM], alf[FM], bhf[FN], blf[FN];
        #pragma unroll
        for (int i = 0; i < FM; ++i) {
            ahf[i] = *(const halfx8*)(sAh + (arow + i * 16 + rr) * 32 + koff);
            alf[i] = *(const halfx8*)(sAl + (arow + i * 16 + rr) * 32 + koff);
        }
        #pragma unroll
        for (int j = 0; j < FN; ++j) {
            bhf[j] = *(const halfx8*)(sBh + (brow + j * 16 + rr) * 32 + koff);
            blf[j] = *(const halfx8*)(sBl + (brow + j * 16 + rr) * 32 + koff);
        }
        #pragma unroll
        for (int i = 0; i < FM; ++i)
            #pragma unroll
            for (int j = 0; j < FN; ++j) {
                acc[i][j] = __builtin_amdgcn_mfma_f32_16x16x32_f16(ahf[i], bhf[j], acc[i][j], 0, 0, 0);
                acc[i][j] = __builtin_amdgcn_mfma_f32_16x16x32_f16(ahf[i], blf[j], acc[i][j], 0, 0, 0);
                acc[i][j] = __builtin_amdgcn_mfma_f32_16x16x32_f16(alf[i], bhf[j], acc[i][j], 0, 0, 0);
            }
        __syncthreads();
    }
}

// ---------------------------------------------------------------------------
// split all static operands to hi/lo fp16 (dtw padded K 48->64) + zero-init
// of `out` fused in the grid tail. float4/thread.
__global__ __launch_bounds__(256) void k_splitall(
        const float* __restrict__ hs,  const float* __restrict__ wip,
        const float* __restrict__ wop, const float* __restrict__ xw,
        const float* __restrict__ dtw,
        _Float16* __restrict__ hsh,  _Float16* __restrict__ hsl,
        _Float16* __restrict__ wiph, _Float16* __restrict__ wipl,
        _Float16* __restrict__ woph, _Float16* __restrict__ wopl,
        _Float16* __restrict__ xwh,  _Float16* __restrict__ xwl,
        _Float16* __restrict__ dtwh, _Float16* __restrict__ dtwl,
        float* __restrict__ outz) {
    int i4 = (blockIdx.x * 256 + threadIdx.x) * 4;
    floatx4 v;
    _Float16 *dh, *dl; int off;
    if (i4 < 786432)        { off = i4;           v = *(const floatx4*)(hs + off);  dh = hsh;  dl = hsl;  }
    else if (i4 < 3145728)  { off = i4 - 786432;  v = *(const floatx4*)(wip + off); dh = wiph; dl = wipl; }
    else if (i4 < 4325376)  { off = i4 - 3145728; v = *(const floatx4*)(wop + off); dh = woph; dl = wopl; }
    else if (i4 < 4816896)  { off = i4 - 4325376; v = *(const floatx4*)(xw + off);  dh = xwh;  dl = xwl;  }
    else if (i4 < 5210112) {
        int t0 = i4 - 4816896;          // [dir*1536 + d][64] padded
        int col = t0 & 63, dr = t0 >> 6;
        floatx4 z = {0.f, 0.f, 0.f, 0.f};
        v = (col < 48) ? *(const floatx4*)(dtw + (size_t)dr * 48 + col) : z;
        dh = dtwh; dl = dtwl; off = t0;
    } else {
        int t0 = i4 - 5210112;          // zero-init out (for outproj atomics)
        floatx4 z = {0.f, 0.f, 0.f, 0.f};
        *(floatx4*)(outz + t0) = z;
        return;
    }
    halfx4 hh, hl;
    #pragma unroll
    for (int e = 0; e < 4; ++e) {
        _Float16 h = (_Float16)v[e];
        hh[e] = h; hl[e] = (_Float16)(v[e] - (float)h);
    }
    *(halfx4*)(dh + off) = hh;
    *(halfx4*)(dl + off) = hl;
}

// ---------------------------------------------------------------------------
// in_proj: (1024x768)*(3072x768)^T, 128x128 tile, K-split 2 -> two partial
// fp32 planes (conv/k_sum sum them). 384 blocks, 48 MFMA : 16 ds_read/chunk.
__global__ __launch_bounds__(256) void k_inproj_t(const _Float16* __restrict__ Ah,
                                                  const _Float16* __restrict__ Al,
                                                  const _Float16* __restrict__ Bh,
                                                  const _Float16* __restrict__ Bl,
                                                  float* __restrict__ C) {
    __shared__ _Float16 smem[128 * 64 + 128 * 64];
    int row0 = blockIdx.x * 128, col0 = blockIdx.y * 128, k0 = blockIdx.z * 384;
    float* Cp = C + (size_t)blockIdx.z * MROWS * F2D;
    floatx4 acc[4][4] = {};
    gemm_core<128, 128, 2, 4, 4>(Ah + (size_t)row0 * EI + k0, Al + (size_t)row0 * EI + k0, EI,
                                 Bh + (size_t)col0 * EI + k0, Bl + (size_t)col0 * EI + k0, EI,
                                 12, smem, acc);
    int lane = threadIdx.x & 63, wave = threadIdx.x >> 6;
    int cc = lane & 15, q = lane >> 4;
    int rbase = row0 + (wave >> 1) * 64, cbase = col0 + (wave & 1) * 64;
    #pragma unroll
    for (int i = 0; i < 4; ++i)
        #pragma unroll
        for (int j = 0; j < 4; ++j)
            #pragma unroll
            for (int r = 0; r < 4; ++r)
                Cp[(size_t)(rbase + i * 16 + q * 4 + r) * F2D + cbase + j * 16 + cc] = acc[i][j][r];
}

// out_proj: (1024x1536)*(768x1536)^T, 64x128 tile, K-split x4,
// atomicAdd directly into out (zero-inited by splitall tail).
__global__ __launch_bounds__(256) void k_outproj_t(const _Float16* __restrict__ Ah,
                                                   const _Float16* __restrict__ Al,
                                                   const _Float16* __restrict__ Bh,
                                                   const _Float16* __restrict__ Bl,
                                                   float* __restrict__ C) {
    __shared__ _Float16 smem[192 * 64];
    int row0 = blockIdx.x * 64, col0 = blockIdx.y * 128, k0 = blockIdx.z * 384;
    floatx4 acc[2][4] = {};
    gemm_core<64, 128, 2, 2, 4>(Ah + (size_t)row0 * DI + k0, Al + (size_t)row0 * DI + k0, DI,
                                Bh + (size_t)col0 * DI + k0, Bl + (size_t)col0 * DI + k0, DI,
                                12, smem, acc);
    int lane = threadIdx.x & 63, wave = threadIdx.x >> 6;
    int cc = lane & 15, q = lane >> 4;
    int rbase = row0 + (wave >> 1) * 32, cbase = col0 + (wave & 1) * 64;
    #pragma unroll
    for (int i = 0; i < 2; ++i)
        #pragma unroll
        for (int j = 0; j < 4; ++j)
            #pragma unroll
            for (int r = 0; r < 4; ++r)
                atomicAdd(&C[(size_t)(rbase + i * 16 + q * 4 + r) * EI + cbase + j * 16 + cc],
                          acc[i][j][r]);
}

// x_dbl: per dir (1024x1536)*(80x1536)^T, K-split x8 -> 8 partial planes
__global__ __launch_bounds__(256) void k_xdbl_t(const _Float16* __restrict__ xh,
                                                const _Float16* __restrict__ xl,
                                                const _Float16* __restrict__ xwh,
                                                const _Float16* __restrict__ xwl,
                                                float* __restrict__ C) {
    __shared__ _Float16 smem[208 * 64];
    int row0 = blockIdx.x * 128, dir = blockIdx.y, k0 = blockIdx.z * 192;
    float* Cp = C + (size_t)blockIdx.z * NDIRS * MROWS * 80;
    floatx4 acc[2][5] = {};
    const size_t abase = ((size_t)dir * MROWS + row0) * DI + k0;
    const size_t bbase = (size_t)dir * 80 * DI + k0;
    gemm_core<128, 80, 1, 2, 5>(xh + abase, xl + abase, DI,
                                xwh + bbase, xwl + bbase, DI, 6, smem, acc);
    int lane = threadIdx.x & 63, wave = threadIdx.x >> 6;
    int cc = lane & 15, q = lane >> 4;
    int rbase = row0 + wave * 32;
    #pragma unroll
    for (int i = 0; i < 2; ++i)
        #pragma unroll
        for (int j = 0; j < 5; ++j)
            #pragma unroll
            for (int r = 0; r < 4; ++r)
                Cp[((size_t)dir * MROWS + rbase + i * 16 + q * 4 + r) * 80 + j * 16 + cc] = acc[i][j][r];
}

// xdbl epilogue: sum 8 partial planes; split cols -> dtq hi/lo (padded to 64),
// interleaved (B,C) pairs into BCm. 96 cols per row (race-free mapping).
__global__ __launch_bounds__(256) void k_xsplit(const float* __restrict__ acc,
                                                _Float16* __restrict__ dtqh,
                                                _Float16* __restrict__ dtql,
                                                float* __restrict__ BCm) {
    const size_t PS = (size_t)NDIRS * MROWS * 80;
    int idx = blockIdx.x * 256 + threadIdx.x;   // < 4*1024*96
    int dir = idx / (MROWS * 96);
    int rem = idx - dir * MROWS * 96;
    int row = rem / 96, col = rem - row * 96;
    size_t rbase = (size_t)dir * MROWS + row;
    auto sum8 = [&](int c) {
        size_t o = rbase * 80 + c;
        float s = 0.f;
        #pragma unroll
        for (int kp = 0; kp < 8; ++kp) s += acc[kp * PS + o];
        return s;
    };
    if (col < 64) {
        float v = (col < 48) ? sum8(col) : 0.f;
        _Float16 h = (_Float16)v;
        dtqh[rbase * 64 + col] = h;
        dtql[rbase * 64 + col] = (_Float16)(v - (float)h);
    } else if (col < 80) {
        int n = col - 64;
        BCm[rbase * 32 + n * 2] = sum8(48 + n);       // B
    } else {
        int n = col - 80;
        BCm[rbase * 32 + n * 2 + 1] = sum8(64 + n);   // C
    }
}

// delta: per dir (1024x64pad)*(1536x64pad)^T, epilogue softplus(.+dtb)
// -> hi/lo fp16 (exact to 2^-22, half the traffic of fp32)
__global__ __launch_bounds__(256) void k_delta_t(const _Float16* __restrict__ dtqh,
                                                 const _Float16* __restrict__ dtql,
                                                 const _Float16* __restrict__ dtwh,
                                                 const _Float16* __restrict__ dtwl,
                                                 const float* __restrict__ dtb,
                                                 _Float16* __restrict__ deltah,
                                                 _Float16* __restrict__ deltal) {
    __shared__ _Float16 smem[192 * 64];
    int row0 = blockIdx.x * 64, col0 = blockIdx.y * 128, dir = blockIdx.z;
    floatx4 acc[2][4] = {};
    const size_t abase = ((size_t)dir * MROWS + row0) * 64;
    const size_t bbase = ((size_t)dir * DI + col0) * 64;
    gemm_core<64, 128, 2, 2, 4>(dtqh + abase, dtql + abase, 64,
                                dtwh + bbase, dtwl + bbase, 64, 2, smem, acc);
    int lane = threadIdx.x & 63, wave = threadIdx.x >> 6;
    int cc = lane & 15, q = lane >> 4;
    int rbase = row0 + (wave >> 1) * 32, cbase = col0 + (wave & 1) * 64;
    #pragma unroll
    for (int i = 0; i < 2; ++i)
        #pragma unroll
        for (int j = 0; j < 4; ++j) {
            int col = cbase + j * 16 + cc;
            float bias = dtb[(size_t)dir * DI + col];
            #pragma unroll
            for (int r = 0; r < 4; ++r) {
                float v = acc[i][j][r] + bias;
                float sp = (v > 20.f) ? v : log1pf(__expf(v));
                size_t o = ((size_t)dir * MROWS + rbase + i * 16 + q * 4 + r) * DI + col;
                _Float16 h = (_Float16)sp;
                deltah[o] = h;
                deltal[o] = (_Float16)(sp - (float)h);
            }
        }
}

// ---------------------------------------------------------------------------
// Depthwise causal conv (K=4) + bias + silu on xz (sum of 2 K-split planes),
// register-window version: thread owns (dir,b,d, 16-l tile).
__global__ __launch_bounds__(256) void k_conv(const float* __restrict__ xz,
                                              const float* __restrict__ cw,
                                              const float* __restrict__ cb,
                                              _Float16* __restrict__ xh,
                                              _Float16* __restrict__ xl) {
    const size_t S = (size_t)MROWS * F2D;
    int dir = blockIdx.z, b = blockIdx.y;
    int lchunk = blockIdx.x / 6, dsub = blockIdx.x % 6;
    int d = dsub * 256 + threadIdx.x;
    int base = lchunk * 16;

    const float* w = cw + ((size_t)dir * DI + d) * KI;
    float w0 = w[0], w1 = w[1], w2 = w[2], w3 = w[3];
    float bias = cb[(size_t)dir * DI + d];

    auto ld = [&](int m) -> float {
        if (m < 0) return 0.f;
        int src = perm_idx(dir, m);
        size_t o = ((size_t)b * 256 + src) * F2D + d;
        return xz[o] + xz[S + o];
    };
    float xm3 = ld(base - 3), xm2 = ld(base - 2), xm1 = ld(base - 1);

    #pragma unroll
    for (int j = 0; j < 16; ++j) {
        float cur = ld(base + j);
        float s = bias + w0 * xm3 + w1 * xm2 + w2 * xm1 + w3 * cur;
        xm3 = xm2; xm2 = xm1; xm1 = cur;
        float x = s / (1.f + __expf(-s));
        _Float16 h = (_Float16)x;
        size_t o = ((size_t)dir * MROWS + b * 256 + base + j) * DI + d;
        xh[o] = h;
        xl[o] = (_Float16)(x - (float)h);
    }
}

// ---------------------------------------------------------------------------
// Selective scan v5: two-phase structure (sY transpose write phase, stores
// OFF the dependent chain), no z (gating in k_sum), delta as hi/lo fp16.
// Block = 32 d x 8 n-pairs; double-buffered LDS; DPP 8-lane reduction.
// ---------------------------------------------------------------------------
__global__ __launch_bounds__(256) void k_scan(const _Float16* __restrict__ deltah,
                                              const _Float16* __restrict__ deltal,
                                              const _Float16* __restrict__ xhg,
                                              const _Float16* __restrict__ xlg,
                                              const float* __restrict__ BCm,
                                              const float* __restrict__ A_log,
                                              const float* __restrict__ Dp,
                                              float* __restrict__ ydir) {
    const int dchunk = blockIdx.x, b = blockIdx.y, dir = blockIdx.z;
    const int tid = threadIdx.x;
    const int dslot = tid >> 3;        // 0..31
    const int np = tid & 7;            // n-pair index
    const int d0 = dchunk * 32, d = d0 + dslot;

    __shared__ float sdx[2][32][64];   // [buf][jj][dslot*2 + {0:delta,1:x}]
    __shared__ float sbc[2][32][32];   // [buf][jj][n*2 + {0:B,1:C}]
    __shared__ float sY[32][32];

    const float Av0 = -__expf(A_log[((size_t)dir * DI + d) * NI + 2 * np]) * LOG2E;
    const float Av1 = -__expf(A_log[((size_t)dir * DI + d) * NI + 2 * np + 1]) * LOG2E;
    const float Dpar = Dp[(size_t)dir * DI + d];
    float h0 = 0.f, h1 = 0.f;

    const size_t dirrow = (size_t)dir * MROWS;
    const int srow = tid >> 3, sc4 = (tid & 7) * 4;   // staging roles

    floatx4 rbc;
    halfx4 rdh, rdl, rxh, rxl;
    auto load_chunk = [&](int j0) {
        int row = b * 256 + j0 + srow;
        size_t o = (dirrow + row) * DI + d0 + sc4;
        rdh = *(const halfx4*)(deltah + o);
        rdl = *(const halfx4*)(deltal + o);
        rxh = *(const halfx4*)(xhg + o);
        rxl = *(const halfx4*)(xlg + o);
        rbc = *(const floatx4*)(BCm + (dirrow + row) * 32 + sc4);
    };

    load_chunk(0);

    for (int c = 0; c < 8; ++c) {
        const int buf = c & 1;
        // stage chunk c
        #pragma unroll
        for (int e = 0; e < 4; ++e) {
            sdx[buf][srow][(sc4 + e) * 2]     = (float)rdh[e] + (float)rdl[e];
            sdx[buf][srow][(sc4 + e) * 2 + 1] = (float)rxh[e] + (float)rxl[e];
        }
        *(floatx4*)&sbc[buf][srow][sc4] = rbc;
        __syncthreads();                       // chunk c visible; sY free
        if (c < 7) load_chunk((c + 1) * 32);   // prefetch, no wait

        // ---- 32 recurrence steps ----
        #pragma unroll
        for (int jj = 0; jj < 32; ++jj) {
            floatx2 dx = *(const floatx2*)&sdx[buf][jj][dslot * 2];
            floatx4 bc = *(const floatx4*)&sbc[buf][jj][np * 4];  // B0,C0,B1,C1
            float dv = dx[0], xv = dx[1];
            float a0 = __builtin_amdgcn_exp2f(dv * Av0);
            float a1 = __builtin_amdgcn_exp2f(dv * Av1);
            float du = dv * xv;
            h0 = fmaf(a0, h0, du * bc[0]);
            h1 = fmaf(a1, h1, du * bc[2]);
            float p = fmaf(h1, bc[3], h0 * bc[1]);
            p = grp8_sum(p);
            if (np == 0) sY[jj][dslot] = fmaf(Dpar, xv, p);
        }
        __syncthreads();                       // sY complete

        // ---- ungated write to out-domain (4 floats/thread, 128B rows) ----
        {
            int lout = perm_idx(dir, c * 32 + srow);
            floatx4 o = *(const floatx4*)&sY[srow][sc4];
            *(floatx4*)&ydir[(dirrow + (size_t)b * 256 + lout) * DI + d0 + sc4] = o;
        }
    }
}

// sum of 4 direction outputs, gate by silu(z) -> hi/lo fp16 for out_proj
__global__ __launch_bounds__(256) void k_sum(const float* __restrict__ ydir,
                                             const float* __restrict__ xz,
                                             _Float16* __restrict__ yh,
                                             _Float16* __restrict__ yl) {
    int i4 = (blockIdx.x * 256 + threadIdx.x) * 4;
    const size_t S = (size_t)MROWS * DI;
    const size_t SZ = (size_t)MROWS * F2D;
    int row = i4 / DI, dcol = i4 - row * DI;
    size_t zo = (size_t)row * F2D + DI + dcol;
    floatx4 zv = *(const floatx4*)(xz + zo) + *(const floatx4*)(xz + SZ + zo);
    floatx4 s = *(const floatx4*)(ydir + i4) + *(const floatx4*)(ydir + S + i4) +
                *(const floatx4*)(ydir + 2 * S + i4) + *(const floatx4*)(ydir + 3 * S + i4);
    halfx4 hh, hl;
    #pragma unroll
    for (int e = 0; e < 4; ++e) {
        float g = zv[e] / (1.f + __expf(-zv[e]));
        float v = s[e] * g;
        _Float16 h = (_Float16)v;
        hh[e] = h; hl[e] = (_Float16)(v - (float)h);
    }
    *(halfx4*)(yh + i4) = hh;
    *(halfx4*)(yl + i4) = hl;
}

// ---------------------------------------------------------------------------
extern "C" void kernel_launch(void* const* d_in, const int* in_sizes, int n_in,
                              void* d_out, int out_size, void* d_ws, size_t ws_size,
                              hipStream_t stream) {
    const float* hs   = (const float*)d_in[0];
    const float* wip  = (const float*)d_in[1];
    const float* wop  = (const float*)d_in[2];
    const float* cw   = (const float*)d_in[3];
    const float* cb   = (const float*)d_in[4];
    const float* xw   = (const float*)d_in[5];
    const float* dtw  = (const float*)d_in[6];
    const float* dtb  = (const float*)d_in[7];
    const float* alog = (const float*)d_in[8];
    const float* dpar = (const float*)d_in[9];
    float* out = (float*)d_out;

    char* p = (char*)d_ws;
    auto alloc_f32 = [&](size_t n) { float* r = (float*)p; p += n * 4; return r; };
    auto alloc_f16 = [&](size_t n) { _Float16* r = (_Float16*)p; p += n * 2; return r; };

    _Float16* hsh  = alloc_f16(786432);
    _Float16* hsl  = alloc_f16(786432);
    _Float16* wiph = alloc_f16(2359296);
    _Float16* wipl = alloc_f16(2359296);
    _Float16* woph = alloc_f16(1179648);
    _Float16* wopl = alloc_f16(1179648);
    _Float16* xwh  = alloc_f16(491520);
    _Float16* xwl  = alloc_f16(491520);
    _Float16* dtwh = alloc_f16((size_t)NDIRS * DI * 64);
    _Float16* dtwl = alloc_f16((size_t)NDIRS * DI * 64);
    float*    xz   = alloc_f32((size_t)2 * MROWS * F2D);   // two K-split planes
    _Float16* xh   = alloc_f16((size_t)NDIRS * MROWS * DI);
    _Float16* xl   = alloc_f16((size_t)NDIRS * MROWS * DI);
    _Float16* dtqh = alloc_f16((size_t)NDIRS * MROWS * 64);
    _Float16* dtql = alloc_f16((size_t)NDIRS * MROWS * 64);
    float*    BCm  = alloc_f32((size_t)NDIRS * MROWS * 32);
    _Float16* deltah = alloc_f16((size_t)NDIRS * MROWS * DI);
    _Float16* deltal = alloc_f16((size_t)NDIRS * MROWS * DI);
    float*    ydir = alloc_f32((size_t)NDIRS * MROWS * DI);
    _Float16* yh   = alloc_f16((size_t)MROWS * DI);
    _Float16* yl   = alloc_f16((size_t)MROWS * DI);

    // alias onto dead region (disjoint lifetimes):
    float* xdba = ydir;    // xdbl 8 planes (10.5 MB <= 25.2 MB); dead after k_xsplit

    k_splitall<<<dim3(5856), 256, 0, stream>>>(hs, wip, wop, xw, dtw,
                                               hsh, hsl, wiph, wipl, woph, wopl,
                                               xwh, xwl, dtwh, dtwl, out);
    k_inproj_t<<<dim3(8, 24, 2), 256, 0, stream>>>(hsh, hsl, wiph, wipl, xz);
    k_conv    <<<dim3(96, BI, NDIRS), 256, 0, stream>>>(xz, cw, cb, xh, xl);
    k_xdbl_t  <<<dim3(8, NDIRS, 8), 256, 0, stream>>>(xh, xl, xwh, xwl, xdba);
    k_xsplit  <<<dim3(1536), 256, 0, stream>>>(xdba, dtqh, dtql, BCm);
    k_delta_t <<<dim3(16, 12, NDIRS), 256, 0, stream>>>(dtqh, dtql, dtwh, dtwl, dtb,
                                                        deltah, deltal);
    k_scan    <<<dim3(DI / 32, BI, NDIRS), 256, 0, stream>>>(deltah, deltal, xh, xl, BCm,
                                                             alog, dpar, ydir);
    k_sum     <<<dim3(1536), 256, 0, stream>>>(ydir, xz, yh, yl);
    k_outproj_t<<<dim3(16, 6, 4), 256, 0, stream>>>(yh, yl, woph, wopl, out);
}

// Round 14
// 233.254 us; speedup vs baseline: 1.0040x; 1.0040x over previous
//
#include <hip/hip_runtime.h>
#include <hip/hip_bf16.h>

#define BI   4
#define LI   256
#define EI   768
#define DI   1536
#define NI   16
#define RI   48
#define KI   4
#define NDIRS 4
#define F2D  3072              // 2*D
#define MROWS 1024             // B*L
#define LOG2E 1.4426950408889634f

typedef float    floatx2 __attribute__((ext_vector_type(2)));
typedef float    floatx4 __attribute__((ext_vector_type(4)));
typedef _Float16 halfx2  __attribute__((ext_vector_type(2)));
typedef _Float16 halfx4  __attribute__((ext_vector_type(4)));
typedef _Float16 halfx8  __attribute__((ext_vector_type(8)));

typedef __attribute__((address_space(3))) unsigned lds_u32;
typedef __attribute__((address_space(1))) const unsigned glb_u32;

__device__ __forceinline__ void load16(const _Float16* g, _Float16* l) {
    __builtin_amdgcn_global_load_lds((glb_u32*)g, (lds_u32*)l, 16, 0, 0);
}

__device__ __forceinline__ int perm_idx(int dir, int j) {
    switch (dir) {
        case 0:  return j;
        case 1:  return 255 - j;
        case 2:  return ((j & 15) << 4) | (j >> 4);
        default: return 255 - (((j & 15) << 4) | (j >> 4));
    }
}

// DPP-based add of a permuted copy (VALU pipe, no LDS traffic).
template<int CTRL>
__device__ __forceinline__ float dpp_add(float p) {
    int t = __builtin_amdgcn_update_dpp(0, __builtin_bit_cast(int, p),
                                        CTRL, 0xf, 0xf, true);
    return p + __builtin_bit_cast(float, t);
}
// sum over 8 consecutive lanes (tid&7 group)
__device__ __forceinline__ float grp8_sum(float p) {
    p = dpp_add<0xB1>(p);    // quad_perm [1,0,3,2]  : xor 1
    p = dpp_add<0x4E>(p);    // quad_perm [2,3,0,1]  : xor 2
    p = dpp_add<0x141>(p);   // row_half_mirror      : combine quads
    return p;
}

// ---------------------------------------------------------------------------
// Tiled hi/lo-fp16 GEMM core. LDS tiles [rows][32] fp16, unpadded
// (global_load_lds lane-order). acc += ah*bh + ah*bl + al*bh.
// ---------------------------------------------------------------------------
template<int BM, int BN, int WGN, int FM, int FN>
__device__ __forceinline__ void gemm_core(const _Float16* __restrict__ Ah,
                                          const _Float16* __restrict__ Al, int lda,
                                          const _Float16* __restrict__ Bh,
                                          const _Float16* __restrict__ Bl, int ldb,
                                          int nChunks, _Float16* smem,
                                          floatx4 (&acc)[FM][FN]) {
    const int tid = threadIdx.x, lane = tid & 63, wave = tid >> 6;
    const int wave_m = wave / WGN, wave_n = wave % WGN;
    _Float16* sAh = smem;
    _Float16* sAl = smem + BM * 32;
    _Float16* sBh = smem + BM * 64;
    _Float16* sBl = smem + BM * 64 + BN * 32;
    const int rr = lane & 15, koff = (lane >> 4) * 8;
    const int arow = wave_m * FM * 16, brow = wave_n * FN * 16;

    for (int c = 0; c < nChunks; ++c) {
        for (int idx = tid; idx < BM * 4; idx += 256) {
            int r = idx >> 2, s = (idx & 3) * 8;
            load16(Ah + (size_t)r * lda + c * 32 + s, sAh + idx * 8);
            load16(Al + (size_t)r * lda + c * 32 + s, sAl + idx * 8);
        }
        for (int idx = tid; idx < BN * 4; idx += 256) {
            int r = idx >> 2, s = (idx & 3) * 8;
            load16(Bh + (size_t)r * ldb + c * 32 + s, sBh + idx * 8);
            load16(Bl + (size_t)r * ldb + c * 32 + s, sBl + idx * 8);
        }
        asm volatile("s_waitcnt vmcnt(0)" ::: "memory");
        __syncthreads();

        halfx8 ahf[FM], alf[FM], bhf[FN], blf[FN];
        #pragma unroll
        for (int i = 0; i < FM; ++i) {
            ahf[i] = *(const halfx8*)(sAh + (arow + i * 16 + rr) * 32 + koff);
            alf[i] = *(const halfx8*)(sAl + (arow + i * 16 + rr) * 32 + koff);
        }
        #pragma unroll
        for (int j = 0; j < FN; ++j) {
            bhf[j] = *(const halfx8*)(sBh + (brow + j * 16 + rr) * 32 + koff);
            blf[j] = *(const halfx8*)(sBl + (brow + j * 16 + rr) * 32 + koff);
        }
        #pragma unroll
        for (int i = 0; i < FM; ++i)
            #pragma unroll
            for (int j = 0; j < FN; ++j) {
                acc[i][j] = __builtin_amdgcn_mfma_f32_16x16x32_f16(ahf[i], bhf[j], acc[i][j], 0, 0, 0);
                acc[i][j] = __builtin_amdgcn_mfma_f32_16x16x32_f16(ahf[i], blf[j], acc[i][j], 0, 0, 0);
                acc[i][j] = __builtin_amdgcn_mfma_f32_16x16x32_f16(alf[i], bhf[j], acc[i][j], 0, 0, 0);
            }
        __syncthreads();
    }
}

// ---------------------------------------------------------------------------
// split all static operands to hi/lo fp16 (dtw padded K 48->64) + zero-init
// of `out` fused in the grid tail. float4/thread.
__global__ __launch_bounds__(256) void k_splitall(
        const float* __restrict__ hs,  const float* __restrict__ wip,
        const float* __restrict__ wop, const float* __restrict__ xw,
        const float* __restrict__ dtw,
        _Float16* __restrict__ hsh,  _Float16* __restrict__ hsl,
        _Float16* __restrict__ wiph, _Float16* __restrict__ wipl,
        _Float16* __restrict__ woph, _Float16* __restrict__ wopl,
        _Float16* __restrict__ xwh,  _Float16* __restrict__ xwl,
        _Float16* __restrict__ dtwh, _Float16* __restrict__ dtwl,
        float* __restrict__ outz) {
    int i4 = (blockIdx.x * 256 + threadIdx.x) * 4;
    floatx4 v;
    _Float16 *dh, *dl; int off;
    if (i4 < 786432)        { off = i4;           v = *(const floatx4*)(hs + off);  dh = hsh;  dl = hsl;  }
    else if (i4 < 3145728)  { off = i4 - 786432;  v = *(const floatx4*)(wip + off); dh = wiph; dl = wipl; }
    else if (i4 < 4325376)  { off = i4 - 3145728; v = *(const floatx4*)(wop + off); dh = woph; dl = wopl; }
    else if (i4 < 4816896)  { off = i4 - 4325376; v = *(const floatx4*)(xw + off);  dh = xwh;  dl = xwl;  }
    else if (i4 < 5210112) {
        int t0 = i4 - 4816896;          // [dir*1536 + d][64] padded
        int col = t0 & 63, dr = t0 >> 6;
        floatx4 z = {0.f, 0.f, 0.f, 0.f};
        v = (col < 48) ? *(const floatx4*)(dtw + (size_t)dr * 48 + col) : z;
        dh = dtwh; dl = dtwl; off = t0;
    } else {
        int t0 = i4 - 5210112;          // zero-init out (for outproj atomics)
        floatx4 z = {0.f, 0.f, 0.f, 0.f};
        *(floatx4*)(outz + t0) = z;
        return;
    }
    halfx4 hh, hl;
    #pragma unroll
    for (int e = 0; e < 4; ++e) {
        _Float16 h = (_Float16)v[e];
        hh[e] = h; hl[e] = (_Float16)(v[e] - (float)h);
    }
    *(halfx4*)(dh + off) = hh;
    *(halfx4*)(dl + off) = hl;
}

// ---------------------------------------------------------------------------
// in_proj: (1024x768)*(3072x768)^T, 128x128 tile, K-split 2 -> two partial
// fp32 planes (conv/k_sum sum them). 384 blocks, 48 MFMA : 16 ds_read/chunk.
__global__ __launch_bounds__(256) void k_inproj_t(const _Float16* __restrict__ Ah,
                                                  const _Float16* __restrict__ Al,
                                                  const _Float16* __restrict__ Bh,
                                                  const _Float16* __restrict__ Bl,
                                                  float* __restrict__ C) {
    __shared__ _Float16 smem[128 * 64 + 128 * 64];
    int row0 = blockIdx.x * 128, col0 = blockIdx.y * 128, k0 = blockIdx.z * 384;
    float* Cp = C + (size_t)blockIdx.z * MROWS * F2D;
    floatx4 acc[4][4] = {};
    gemm_core<128, 128, 2, 4, 4>(Ah + (size_t)row0 * EI + k0, Al + (size_t)row0 * EI + k0, EI,
                                 Bh + (size_t)col0 * EI + k0, Bl + (size_t)col0 * EI + k0, EI,
                                 12, smem, acc);
    int lane = threadIdx.x & 63, wave = threadIdx.x >> 6;
    int cc = lane & 15, q = lane >> 4;
    int rbase = row0 + (wave >> 1) * 64, cbase = col0 + (wave & 1) * 64;
    #pragma unroll
    for (int i = 0; i < 4; ++i)
        #pragma unroll
        for (int j = 0; j < 4; ++j)
            #pragma unroll
            for (int r = 0; r < 4; ++r)
                Cp[(size_t)(rbase + i * 16 + q * 4 + r) * F2D + cbase + j * 16 + cc] = acc[i][j][r];
}

// out_proj: (1024x1536)*(768x1536)^T, 64x128 tile, K-split x4,
// atomicAdd directly into out (zero-inited by splitall tail).
__global__ __launch_bounds__(256) void k_outproj_t(const _Float16* __restrict__ Ah,
                                                   const _Float16* __restrict__ Al,
                                                   const _Float16* __restrict__ Bh,
                                                   const _Float16* __restrict__ Bl,
                                                   float* __restrict__ C) {
    __shared__ _Float16 smem[192 * 64];
    int row0 = blockIdx.x * 64, col0 = blockIdx.y * 128, k0 = blockIdx.z * 384;
    floatx4 acc[2][4] = {};
    gemm_core<64, 128, 2, 2, 4>(Ah + (size_t)row0 * DI + k0, Al + (size_t)row0 * DI + k0, DI,
                                Bh + (size_t)col0 * DI + k0, Bl + (size_t)col0 * DI + k0, DI,
                                12, smem, acc);
    int lane = threadIdx.x & 63, wave = threadIdx.x >> 6;
    int cc = lane & 15, q = lane >> 4;
    int rbase = row0 + (wave >> 1) * 32, cbase = col0 + (wave & 1) * 64;
    #pragma unroll
    for (int i = 0; i < 2; ++i)
        #pragma unroll
        for (int j = 0; j < 4; ++j)
            #pragma unroll
            for (int r = 0; r < 4; ++r)
                atomicAdd(&C[(size_t)(rbase + i * 16 + q * 4 + r) * EI + cbase + j * 16 + cc],
                          acc[i][j][r]);
}

// x_dbl: per dir (1024x1536)*(80x1536)^T, K-split x8 -> 8 partial planes
__global__ __launch_bounds__(256) void k_xdbl_t(const _Float16* __restrict__ xh,
                                                const _Float16* __restrict__ xl,
                                                const _Float16* __restrict__ xwh,
                                                const _Float16* __restrict__ xwl,
                                                float* __restrict__ C) {
    __shared__ _Float16 smem[208 * 64];
    int row0 = blockIdx.x * 128, dir = blockIdx.y, k0 = blockIdx.z * 192;
    float* Cp = C + (size_t)blockIdx.z * NDIRS * MROWS * 80;
    floatx4 acc[2][5] = {};
    const size_t abase = ((size_t)dir * MROWS + row0) * DI + k0;
    const size_t bbase = (size_t)dir * 80 * DI + k0;
    gemm_core<128, 80, 1, 2, 5>(xh + abase, xl + abase, DI,
                                xwh + bbase, xwl + bbase, DI, 6, smem, acc);
    int lane = threadIdx.x & 63, wave = threadIdx.x >> 6;
    int cc = lane & 15, q = lane >> 4;
    int rbase = row0 + wave * 32;
    #pragma unroll
    for (int i = 0; i < 2; ++i)
        #pragma unroll
        for (int j = 0; j < 5; ++j)
            #pragma unroll
            for (int r = 0; r < 4; ++r)
                Cp[((size_t)dir * MROWS + rbase + i * 16 + q * 4 + r) * 80 + j * 16 + cc] = acc[i][j][r];
}

// xdbl epilogue: sum 8 partial planes; split cols -> dtq hi/lo (padded to 64),
// interleaved (B,C) pairs into BCm. 96 cols per row (race-free mapping).
__global__ __launch_bounds__(256) void k_xsplit(const float* __restrict__ acc,
                                                _Float16* __restrict__ dtqh,
                                                _Float16* __restrict__ dtql,
                                                float* __restrict__ BCm) {
    const size_t PS = (size_t)NDIRS * MROWS * 80;
    int idx = blockIdx.x * 256 + threadIdx.x;   // < 4*1024*96
    int dir = idx / (MROWS * 96);
    int rem = idx - dir * MROWS * 96;
    int row = rem / 96, col = rem - row * 96;
    size_t rbase = (size_t)dir * MROWS + row;
    auto sum8 = [&](int c) {
        size_t o = rbase * 80 + c;
        float s = 0.f;
        #pragma unroll
        for (int kp = 0; kp < 8; ++kp) s += acc[kp * PS + o];
        return s;
    };
    if (col < 64) {
        float v = (col < 48) ? sum8(col) : 0.f;
        _Float16 h = (_Float16)v;
        dtqh[rbase * 64 + col] = h;
        dtql[rbase * 64 + col] = (_Float16)(v - (float)h);
    } else if (col < 80) {
        int n = col - 64;
        BCm[rbase * 32 + n * 2] = sum8(48 + n);       // B
    } else {
        int n = col - 80;
        BCm[rbase * 32 + n * 2 + 1] = sum8(64 + n);   // C
    }
}

// delta: per dir (1024x64pad)*(1536x64pad)^T, epilogue softplus(.+dtb) -> fp32
__global__ __launch_bounds__(256) void k_delta_t(const _Float16* __restrict__ dtqh,
                                                 const _Float16* __restrict__ dtql,
                                                 const _Float16* __restrict__ dtwh,
                                                 const _Float16* __restrict__ dtwl,
                                                 const float* __restrict__ dtb,
                                                 float* __restrict__ delta) {
    __shared__ _Float16 smem[192 * 64];
    int row0 = blockIdx.x * 64, col0 = blockIdx.y * 128, dir = blockIdx.z;
    floatx4 acc[2][4] = {};
    const size_t abase = ((size_t)dir * MROWS + row0) * 64;
    const size_t bbase = ((size_t)dir * DI + col0) * 64;
    gemm_core<64, 128, 2, 2, 4>(dtqh + abase, dtql + abase, 64,
                                dtwh + bbase, dtwl + bbase, 64, 2, smem, acc);
    int lane = threadIdx.x & 63, wave = threadIdx.x >> 6;
    int cc = lane & 15, q = lane >> 4;
    int rbase = row0 + (wave >> 1) * 32, cbase = col0 + (wave & 1) * 64;
    #pragma unroll
    for (int i = 0; i < 2; ++i)
        #pragma unroll
        for (int j = 0; j < 4; ++j) {
            int col = cbase + j * 16 + cc;
            float bias = dtb[(size_t)dir * DI + col];
            #pragma unroll
            for (int r = 0; r < 4; ++r) {
                float v = acc[i][j][r] + bias;
                float sp = (v > 20.f) ? v : log1pf(__expf(v));
                delta[((size_t)dir * MROWS + rbase + i * 16 + q * 4 + r) * DI + col] = sp;
            }
        }
}

// ---------------------------------------------------------------------------
// Depthwise causal conv (K=4) + bias + silu on xz (sum of 2 K-split planes),
// register-window version: thread owns (dir,b,d, 16-l tile).
__global__ __launch_bounds__(256) void k_conv(const float* __restrict__ xz,
                                              const float* __restrict__ cw,
                                              const float* __restrict__ cb,
                                              _Float16* __restrict__ xh,
                                              _Float16* __restrict__ xl) {
    const size_t S = (size_t)MROWS * F2D;
    int dir = blockIdx.z, b = blockIdx.y;
    int lchunk = blockIdx.x / 6, dsub = blockIdx.x % 6;
    int d = dsub * 256 + threadIdx.x;
    int base = lchunk * 16;

    const float* w = cw + ((size_t)dir * DI + d) * KI;
    float w0 = w[0], w1 = w[1], w2 = w[2], w3 = w[3];
    float bias = cb[(size_t)dir * DI + d];

    auto ld = [&](int m) -> float {
        if (m < 0) return 0.f;
        int src = perm_idx(dir, m);
        size_t o = ((size_t)b * 256 + src) * F2D + d;
        return xz[o] + xz[S + o];
    };
    float xm3 = ld(base - 3), xm2 = ld(base - 2), xm1 = ld(base - 1);

    #pragma unroll
    for (int j = 0; j < 16; ++j) {
        float cur = ld(base + j);
        float s = bias + w0 * xm3 + w1 * xm2 + w2 * xm1 + w3 * cur;
        xm3 = xm2; xm2 = xm1; xm1 = cur;
        float x = s / (1.f + __expf(-s));
        _Float16 h = (_Float16)x;
        size_t o = ((size_t)dir * MROWS + b * 256 + base + j) * DI + d;
        xh[o] = h;
        xl[o] = (_Float16)(x - (float)h);
    }
}

// ---------------------------------------------------------------------------
// Selective scan v5: two-phase structure (sY transpose write phase, stores
// OFF the dependent chain), no z (gating in k_sum), delta fp32.
// Block = 32 d x 8 n-pairs; double-buffered LDS; DPP 8-lane reduction.
// ---------------------------------------------------------------------------
__global__ __launch_bounds__(256) void k_scan(const float* __restrict__ delta,
                                              const _Float16* __restrict__ xhg,
                                              const _Float16* __restrict__ xlg,
                                              const float* __restrict__ BCm,
                                              const float* __restrict__ A_log,
                                              const float* __restrict__ Dp,
                                              float* __restrict__ ydir) {
    const int dchunk = blockIdx.x, b = blockIdx.y, dir = blockIdx.z;
    const int tid = threadIdx.x;
    const int dslot = tid >> 3;        // 0..31
    const int np = tid & 7;            // n-pair index
    const int d0 = dchunk * 32, d = d0 + dslot;

    __shared__ float sdx[2][32][64];   // [buf][jj][dslot*2 + {0:delta,1:x}]
    __shared__ float sbc[2][32][32];   // [buf][jj][n*2 + {0:B,1:C}]
    __shared__ float sY[32][32];

    const float Av0 = -__expf(A_log[((size_t)dir * DI + d) * NI + 2 * np]) * LOG2E;
    const float Av1 = -__expf(A_log[((size_t)dir * DI + d) * NI + 2 * np + 1]) * LOG2E;
    const float Dpar = Dp[(size_t)dir * DI + d];
    float h0 = 0.f, h1 = 0.f;

    const size_t dirrow = (size_t)dir * MROWS;
    const int srow = tid >> 3, sc4 = (tid & 7) * 4;   // staging roles

    floatx4 rdel, rbc;
    halfx4 rxh, rxl;
    auto load_chunk = [&](int j0) {
        int row = b * 256 + j0 + srow;
        size_t o = (dirrow + row) * DI + d0 + sc4;
        rdel = *(const floatx4*)(delta + o);
        rxh  = *(const halfx4*)(xhg + o);
        rxl  = *(const halfx4*)(xlg + o);
        rbc  = *(const floatx4*)(BCm + (dirrow + row) * 32 + sc4);
    };

    load_chunk(0);

    for (int c = 0; c < 8; ++c) {
        const int buf = c & 1;
        // stage chunk c
        #pragma unroll
        for (int e = 0; e < 4; ++e) {
            sdx[buf][srow][(sc4 + e) * 2]     = rdel[e];
            sdx[buf][srow][(sc4 + e) * 2 + 1] = (float)rxh[e] + (float)rxl[e];
        }
        *(floatx4*)&sbc[buf][srow][sc4] = rbc;
        __syncthreads();                       // chunk c visible; sY free
        if (c < 7) load_chunk((c + 1) * 32);   // prefetch, no wait

        // ---- 32 recurrence steps ----
        #pragma unroll
        for (int jj = 0; jj < 32; ++jj) {
            floatx2 dx = *(const floatx2*)&sdx[buf][jj][dslot * 2];
            floatx4 bc = *(const floatx4*)&sbc[buf][jj][np * 4];  // B0,C0,B1,C1
            float dv = dx[0], xv = dx[1];
            float a0 = __builtin_amdgcn_exp2f(dv * Av0);
            float a1 = __builtin_amdgcn_exp2f(dv * Av1);
            float du = dv * xv;
            h0 = fmaf(a0, h0, du * bc[0]);
            h1 = fmaf(a1, h1, du * bc[2]);
            float p = fmaf(h1, bc[3], h0 * bc[1]);
            p = grp8_sum(p);
            if (np == 0) sY[jj][dslot] = fmaf(Dpar, xv, p);
        }
        __syncthreads();                       // sY complete

        // ---- ungated write to out-domain (4 floats/thread, 128B rows) ----
        {
            int lout = perm_idx(dir, c * 32 + srow);
            floatx4 o = *(const floatx4*)&sY[srow][sc4];
            *(floatx4*)&ydir[(dirrow + (size_t)b * 256 + lout) * DI + d0 + sc4] = o;
        }
    }
}

// sum of 4 direction outputs, gate by silu(z) -> hi/lo fp16 for out_proj
__global__ __launch_bounds__(256) void k_sum(const float* __restrict__ ydir,
                                             const float* __restrict__ xz,
                                             _Float16* __restrict__ yh,
                                             _Float16* __restrict__ yl) {
    int i4 = (blockIdx.x * 256 + threadIdx.x) * 4;
    const size_t S = (size_t)MROWS * DI;
    const size_t SZ = (size_t)MROWS * F2D;
    int row = i4 / DI, dcol = i4 - row * DI;
    size_t zo = (size_t)row * F2D + DI + dcol;
    floatx4 zv = *(const floatx4*)(xz + zo) + *(const floatx4*)(xz + SZ + zo);
    floatx4 s = *(const floatx4*)(ydir + i4) + *(const floatx4*)(ydir + S + i4) +
                *(const floatx4*)(ydir + 2 * S + i4) + *(const floatx4*)(ydir + 3 * S + i4);
    halfx4 hh, hl;
    #pragma unroll
    for (int e = 0; e < 4; ++e) {
        float g = zv[e] / (1.f + __expf(-zv[e]));
        float v = s[e] * g;
        _Float16 h = (_Float16)v;
        hh[e] = h; hl[e] = (_Float16)(v - (float)h);
    }
    *(halfx4*)(yh + i4) = hh;
    *(halfx4*)(yl + i4) = hl;
}

// ---------------------------------------------------------------------------
extern "C" void kernel_launch(void* const* d_in, const int* in_sizes, int n_in,
                              void* d_out, int out_size, void* d_ws, size_t ws_size,
                              hipStream_t stream) {
    const float* hs   = (const float*)d_in[0];
    const float* wip  = (const float*)d_in[1];
    const float* wop  = (const float*)d_in[2];
    const float* cw   = (const float*)d_in[3];
    const float* cb   = (const float*)d_in[4];
    const float* xw   = (const float*)d_in[5];
    const float* dtw  = (const float*)d_in[6];
    const float* dtb  = (const float*)d_in[7];
    const float* alog = (const float*)d_in[8];
    const float* dpar = (const float*)d_in[9];
    float* out = (float*)d_out;

    char* p = (char*)d_ws;
    auto alloc_f32 = [&](size_t n) { float* r = (float*)p; p += n * 4; return r; };
    auto alloc_f16 = [&](size_t n) { _Float16* r = (_Float16*)p; p += n * 2; return r; };

    _Float16* hsh  = alloc_f16(786432);
    _Float16* hsl  = alloc_f16(786432);
    _Float16* wiph = alloc_f16(2359296);
    _Float16* wipl = alloc_f16(2359296);
    _Float16* woph = alloc_f16(1179648);
    _Float16* wopl = alloc_f16(1179648);
    _Float16* xwh  = alloc_f16(491520);
    _Float16* xwl  = alloc_f16(491520);
    _Float16* dtwh = alloc_f16((size_t)NDIRS * DI * 64);
    _Float16* dtwl = alloc_f16((size_t)NDIRS * DI * 64);
    float*    xz   = alloc_f32((size_t)2 * MROWS * F2D);   // two K-split planes
    _Float16* xh   = alloc_f16((size_t)NDIRS * MROWS * DI);
    _Float16* xl   = alloc_f16((size_t)NDIRS * MROWS * DI);
    _Float16* dtqh = alloc_f16((size_t)NDIRS * MROWS * 64);
    _Float16* dtql = alloc_f16((size_t)NDIRS * MROWS * 64);
    float*    BCm  = alloc_f32((size_t)NDIRS * MROWS * 32);
    float*    delta= alloc_f32((size_t)NDIRS * MROWS * DI);
    float*    ydir = alloc_f32((size_t)NDIRS * MROWS * DI);
    _Float16* yh   = alloc_f16((size_t)MROWS * DI);
    _Float16* yl   = alloc_f16((size_t)MROWS * DI);

    // alias onto dead region (disjoint lifetimes):
    float* xdba = ydir;    // xdbl 8 planes (10.5 MB <= 25.2 MB); dead after k_xsplit

    k_splitall<<<dim3(5856), 256, 0, stream>>>(hs, wip, wop, xw, dtw,
                                               hsh, hsl, wiph, wipl, woph, wopl,
                                               xwh, xwl, dtwh, dtwl, out);
    k_inproj_t<<<dim3(8, 24, 2), 256, 0, stream>>>(hsh, hsl, wiph, wipl, xz);
    k_conv    <<<dim3(96, BI, NDIRS), 256, 0, stream>>>(xz, cw, cb, xh, xl);
    k_xdbl_t  <<<dim3(8, NDIRS, 8), 256, 0, stream>>>(xh, xl, xwh, xwl, xdba);
    k_xsplit  <<<dim3(1536), 256, 0, stream>>>(xdba, dtqh, dtql, BCm);
    k_delta_t <<<dim3(16, 12, NDIRS), 256, 0, stream>>>(dtqh, dtql, dtwh, dtwl, dtb, delta);
    k_scan    <<<dim3(DI / 32, BI, NDIRS), 256, 0, stream>>>(delta, xh, xl, BCm,
                                                             alog, dpar, ydir);
    k_sum     <<<dim3(1536), 256, 0, stream>>>(ydir, xz, yh, yl);
    k_outproj_t<<<dim3(16, 6, 4), 256, 0, stream>>>(yh, yl, woph, wopl, out);
}

// Round 15
// 228.026 us; speedup vs baseline: 1.0271x; 1.0229x over previous
//
#include <hip/hip_runtime.h>
#include <hip/hip_bf16.h>

#define BI   4
#define LI   256
#define EI   768
#define DI   1536
#define NI   16
#define RI   48
#define KI   4
#define NDIRS 4
#define F2D  3072              // 2*D
#define MROWS 1024             // B*L
#define LOG2E 1.4426950408889634f

typedef float    floatx2 __attribute__((ext_vector_type(2)));
typedef float    floatx4 __attribute__((ext_vector_type(4)));
typedef _Float16 halfx2  __attribute__((ext_vector_type(2)));
typedef _Float16 halfx4  __attribute__((ext_vector_type(4)));
typedef _Float16 halfx8  __attribute__((ext_vector_type(8)));

typedef __attribute__((address_space(3))) unsigned lds_u32;
typedef __attribute__((address_space(1))) const unsigned glb_u32;

__device__ __forceinline__ void load16(const _Float16* g, _Float16* l) {
    __builtin_amdgcn_global_load_lds((glb_u32*)g, (lds_u32*)l, 16, 0, 0);
}

__device__ __forceinline__ int perm_idx(int dir, int j) {
    switch (dir) {
        case 0:  return j;
        case 1:  return 255 - j;
        case 2:  return ((j & 15) << 4) | (j >> 4);
        default: return 255 - (((j & 15) << 4) | (j >> 4));
    }
}

// DPP-based add of a permuted copy (VALU pipe, no LDS traffic).
template<int CTRL>
__device__ __forceinline__ float dpp_add(float p) {
    int t = __builtin_amdgcn_update_dpp(0, __builtin_bit_cast(int, p),
                                        CTRL, 0xf, 0xf, true);
    return p + __builtin_bit_cast(float, t);
}
// sum over 8 consecutive lanes (tid&7 group)
__device__ __forceinline__ float grp8_sum(float p) {
    p = dpp_add<0xB1>(p);    // quad_perm [1,0,3,2]  : xor 1
    p = dpp_add<0x4E>(p);    // quad_perm [2,3,0,1]  : xor 2
    p = dpp_add<0x141>(p);   // row_half_mirror      : combine quads
    return p;
}

// ---------------------------------------------------------------------------
// Tiled hi/lo-fp16 GEMM core. LDS tiles [rows][32] fp16, unpadded
// (global_load_lds lane-order). acc += ah*bh + ah*bl + al*bh.
// ---------------------------------------------------------------------------
template<int BM, int BN, int WGN, int FM, int FN>
__device__ __forceinline__ void gemm_core(const _Float16* __restrict__ Ah,
                                          const _Float16* __restrict__ Al, int lda,
                                          const _Float16* __restrict__ Bh,
                                          const _Float16* __restrict__ Bl, int ldb,
                                          int nChunks, _Float16* smem,
                                          floatx4 (&acc)[FM][FN]) {
    const int tid = threadIdx.x, lane = tid & 63, wave = tid >> 6;
    const int wave_m = wave / WGN, wave_n = wave % WGN;
    _Float16* sAh = smem;
    _Float16* sAl = smem + BM * 32;
    _Float16* sBh = smem + BM * 64;
    _Float16* sBl = smem + BM * 64 + BN * 32;
    const int rr = lane & 15, koff = (lane >> 4) * 8;
    const int arow = wave_m * FM * 16, brow = wave_n * FN * 16;

    for (int c = 0; c < nChunks; ++c) {
        for (int idx = tid; idx < BM * 4; idx += 256) {
            int r = idx >> 2, s = (idx & 3) * 8;
            load16(Ah + (size_t)r * lda + c * 32 + s, sAh + idx * 8);
            load16(Al + (size_t)r * lda + c * 32 + s, sAl + idx * 8);
        }
        for (int idx = tid; idx < BN * 4; idx += 256) {
            int r = idx >> 2, s = (idx & 3) * 8;
            load16(Bh + (size_t)r * ldb + c * 32 + s, sBh + idx * 8);
            load16(Bl + (size_t)r * ldb + c * 32 + s, sBl + idx * 8);
        }
        asm volatile("s_waitcnt vmcnt(0)" ::: "memory");
        __syncthreads();

        halfx8 ahf[FM], alf[FM], bhf[FN], blf[FN];
        #pragma unroll
        for (int i = 0; i < FM; ++i) {
            ahf[i] = *(const halfx8*)(sAh + (arow + i * 16 + rr) * 32 + koff);
            alf[i] = *(const halfx8*)(sAl + (arow + i * 16 + rr) * 32 + koff);
        }
        #pragma unroll
        for (int j = 0; j < FN; ++j) {
            bhf[j] = *(const halfx8*)(sBh + (brow + j * 16 + rr) * 32 + koff);
            blf[j] = *(const halfx8*)(sBl + (brow + j * 16 + rr) * 32 + koff);
        }
        #pragma unroll
        for (int i = 0; i < FM; ++i)
            #pragma unroll
            for (int j = 0; j < FN; ++j) {
                acc[i][j] = __builtin_amdgcn_mfma_f32_16x16x32_f16(ahf[i], bhf[j], acc[i][j], 0, 0, 0);
                acc[i][j] = __builtin_amdgcn_mfma_f32_16x16x32_f16(ahf[i], blf[j], acc[i][j], 0, 0, 0);
                acc[i][j] = __builtin_amdgcn_mfma_f32_16x16x32_f16(alf[i], bhf[j], acc[i][j], 0, 0, 0);
            }
        __syncthreads();
    }
}

// ---------------------------------------------------------------------------
// split all static operands to hi/lo fp16 (dtw padded K 48->64), float4/thread
__global__ __launch_bounds__(256) void k_splitall(
        const float* __restrict__ hs,  const float* __restrict__ wip,
        const float* __restrict__ wop, const float* __restrict__ xw,
        const float* __restrict__ dtw,
        _Float16* __restrict__ hsh,  _Float16* __restrict__ hsl,
        _Float16* __restrict__ wiph, _Float16* __restrict__ wipl,
        _Float16* __restrict__ woph, _Float16* __restrict__ wopl,
        _Float16* __restrict__ xwh,  _Float16* __restrict__ xwl,
        _Float16* __restrict__ dtwh, _Float16* __restrict__ dtwl) {
    int i4 = (blockIdx.x * 256 + threadIdx.x) * 4;
    floatx4 v;
    _Float16 *dh, *dl; int off;
    if (i4 < 786432)        { off = i4;           v = *(const floatx4*)(hs + off);  dh = hsh;  dl = hsl;  }
    else if (i4 < 3145728)  { off = i4 - 786432;  v = *(const floatx4*)(wip + off); dh = wiph; dl = wipl; }
    else if (i4 < 4325376)  { off = i4 - 3145728; v = *(const floatx4*)(wop + off); dh = woph; dl = wopl; }
    else if (i4 < 4816896)  { off = i4 - 4325376; v = *(const floatx4*)(xw + off);  dh = xwh;  dl = xwl;  }
    else {
        int t0 = i4 - 4816896;          // [dir*1536 + d][64] padded
        int col = t0 & 63, dr = t0 >> 6;
        floatx4 z = {0.f, 0.f, 0.f, 0.f};
        v = (col < 48) ? *(const floatx4*)(dtw + (size_t)dr * 48 + col) : z;
        dh = dtwh; dl = dtwl; off = t0;
    }
    halfx4 hh, hl;
    #pragma unroll
    for (int e = 0; e < 4; ++e) {
        _Float16 h = (_Float16)v[e];
        hh[e] = h; hl[e] = (_Float16)(v[e] - (float)h);
    }
    *(halfx4*)(dh + off) = hh;
    *(halfx4*)(dl + off) = hl;
}

// ---------------------------------------------------------------------------
// in_proj: (1024x768)*(3072x768)^T, 128x128 tile, K-split 2 -> two partial
// fp32 planes (conv/k_sum sum them). 384 blocks, 48 MFMA : 16 ds_read/chunk.
__global__ __launch_bounds__(256) void k_inproj_t(const _Float16* __restrict__ Ah,
                                                  const _Float16* __restrict__ Al,
                                                  const _Float16* __restrict__ Bh,
                                                  const _Float16* __restrict__ Bl,
                                                  float* __restrict__ C) {
    __shared__ _Float16 smem[128 * 64 + 128 * 64];
    int row0 = blockIdx.x * 128, col0 = blockIdx.y * 128, k0 = blockIdx.z * 384;
    float* Cp = C + (size_t)blockIdx.z * MROWS * F2D;
    floatx4 acc[4][4] = {};
    gemm_core<128, 128, 2, 4, 4>(Ah + (size_t)row0 * EI + k0, Al + (size_t)row0 * EI + k0, EI,
                                 Bh + (size_t)col0 * EI + k0, Bl + (size_t)col0 * EI + k0, EI,
                                 12, smem, acc);
    int lane = threadIdx.x & 63, wave = threadIdx.x >> 6;
    int cc = lane & 15, q = lane >> 4;
    int rbase = row0 + (wave >> 1) * 64, cbase = col0 + (wave & 1) * 64;
    #pragma unroll
    for (int i = 0; i < 4; ++i)
        #pragma unroll
        for (int j = 0; j < 4; ++j)
            #pragma unroll
            for (int r = 0; r < 4; ++r)
                Cp[(size_t)(rbase + i * 16 + q * 4 + r) * F2D + cbase + j * 16 + cc] = acc[i][j][r];
}

// out_proj: (1024x1536)*(768x1536)^T, 64x128 tile, K-split x4 -> 4 planes
__global__ __launch_bounds__(256) void k_outproj_t(const _Float16* __restrict__ Ah,
                                                   const _Float16* __restrict__ Al,
                                                   const _Float16* __restrict__ Bh,
                                                   const _Float16* __restrict__ Bl,
                                                   float* __restrict__ C) {
    __shared__ _Float16 smem[192 * 64];
    int row0 = blockIdx.x * 64, col0 = blockIdx.y * 128, k0 = blockIdx.z * 384;
    float* Cp = C + (size_t)blockIdx.z * MROWS * EI;
    floatx4 acc[2][4] = {};
    gemm_core<64, 128, 2, 2, 4>(Ah + (size_t)row0 * DI + k0, Al + (size_t)row0 * DI + k0, DI,
                                Bh + (size_t)col0 * DI + k0, Bl + (size_t)col0 * DI + k0, DI,
                                12, smem, acc);
    int lane = threadIdx.x & 63, wave = threadIdx.x >> 6;
    int cc = lane & 15, q = lane >> 4;
    int rbase = row0 + (wave >> 1) * 32, cbase = col0 + (wave & 1) * 64;
    #pragma unroll
    for (int i = 0; i < 2; ++i)
        #pragma unroll
        for (int j = 0; j < 4; ++j)
            #pragma unroll
            for (int r = 0; r < 4; ++r)
                Cp[(size_t)(rbase + i * 16 + q * 4 + r) * EI + cbase + j * 16 + cc] = acc[i][j][r];
}

// final out = sum of 4 out_proj partial planes
__global__ __launch_bounds__(256) void k_osum(const float* __restrict__ oacc,
                                              float* __restrict__ out) {
    int i4 = (blockIdx.x * 256 + threadIdx.x) * 4;
    const size_t S = (size_t)MROWS * EI;
    floatx4 s = *(const floatx4*)(oacc + i4) + *(const floatx4*)(oacc + S + i4) +
                *(const floatx4*)(oacc + 2 * S + i4) + *(const floatx4*)(oacc + 3 * S + i4);
    *(floatx4*)(out + i4) = s;
}

// x_dbl: per dir (1024x1536)*(80x1536)^T, K-split x8 -> 8 partial planes
__global__ __launch_bounds__(256) void k_xdbl_t(const _Float16* __restrict__ xh,
                                                const _Float16* __restrict__ xl,
                                                const _Float16* __restrict__ xwh,
                                                const _Float16* __restrict__ xwl,
                                                float* __restrict__ C) {
    __shared__ _Float16 smem[208 * 64];
    int row0 = blockIdx.x * 128, dir = blockIdx.y, k0 = blockIdx.z * 192;
    float* Cp = C + (size_t)blockIdx.z * NDIRS * MROWS * 80;
    floatx4 acc[2][5] = {};
    const size_t abase = ((size_t)dir * MROWS + row0) * DI + k0;
    const size_t bbase = (size_t)dir * 80 * DI + k0;
    gemm_core<128, 80, 1, 2, 5>(xh + abase, xl + abase, DI,
                                xwh + bbase, xwl + bbase, DI, 6, smem, acc);
    int lane = threadIdx.x & 63, wave = threadIdx.x >> 6;
    int cc = lane & 15, q = lane >> 4;
    int rbase = row0 + wave * 32;
    #pragma unroll
    for (int i = 0; i < 2; ++i)
        #pragma unroll
        for (int j = 0; j < 5; ++j)
            #pragma unroll
            for (int r = 0; r < 4; ++r)
                Cp[((size_t)dir * MROWS + rbase + i * 16 + q * 4 + r) * 80 + j * 16 + cc] = acc[i][j][r];
}

// xdbl epilogue: sum 8 partial planes; split cols -> dtq hi/lo (padded to 64),
// interleaved (B,C) pairs into BCm. 96 cols per row (race-free mapping).
__global__ __launch_bounds__(256) void k_xsplit(const float* __restrict__ acc,
                                                _Float16* __restrict__ dtqh,
                                                _Float16* __restrict__ dtql,
                                                float* __restrict__ BCm) {
    const size_t PS = (size_t)NDIRS * MROWS * 80;
    int idx = blockIdx.x * 256 + threadIdx.x;   // < 4*1024*96
    int dir = idx / (MROWS * 96);
    int rem = idx - dir * MROWS * 96;
    int row = rem / 96, col = rem - row * 96;
    size_t rbase = (size_t)dir * MROWS + row;
    auto sum8 = [&](int c) {
        size_t o = rbase * 80 + c;
        float s = 0.f;
        #pragma unroll
        for (int kp = 0; kp < 8; ++kp) s += acc[kp * PS + o];
        return s;
    };
    if (col < 64) {
        float v = (col < 48) ? sum8(col) : 0.f;
        _Float16 h = (_Float16)v;
        dtqh[rbase * 64 + col] = h;
        dtql[rbase * 64 + col] = (_Float16)(v - (float)h);
    } else if (col < 80) {
        int n = col - 64;
        BCm[rbase * 32 + n * 2] = sum8(48 + n);       // B
    } else {
        int n = col - 80;
        BCm[rbase * 32 + n * 2 + 1] = sum8(64 + n);   // C
    }
}

// delta: per dir (1024x64pad)*(1536x64pad)^T, epilogue softplus(.+dtb) -> fp32
__global__ __launch_bounds__(256) void k_delta_t(const _Float16* __restrict__ dtqh,
                                                 const _Float16* __restrict__ dtql,
                                                 const _Float16* __restrict__ dtwh,
                                                 const _Float16* __restrict__ dtwl,
                                                 const float* __restrict__ dtb,
                                                 float* __restrict__ delta) {
    __shared__ _Float16 smem[192 * 64];
    int row0 = blockIdx.x * 64, col0 = blockIdx.y * 128, dir = blockIdx.z;
    floatx4 acc[2][4] = {};
    const size_t abase = ((size_t)dir * MROWS + row0) * 64;
    const size_t bbase = ((size_t)dir * DI + col0) * 64;
    gemm_core<64, 128, 2, 2, 4>(dtqh + abase, dtql + abase, 64,
                                dtwh + bbase, dtwl + bbase, 64, 2, smem, acc);
    int lane = threadIdx.x & 63, wave = threadIdx.x >> 6;
    int cc = lane & 15, q = lane >> 4;
    int rbase = row0 + (wave >> 1) * 32, cbase = col0 + (wave & 1) * 64;
    #pragma unroll
    for (int i = 0; i < 2; ++i)
        #pragma unroll
        for (int j = 0; j < 4; ++j) {
            int col = cbase + j * 16 + cc;
            float bias = dtb[(size_t)dir * DI + col];
            #pragma unroll
            for (int r = 0; r < 4; ++r) {
                float v = acc[i][j][r] + bias;
                float sp = (v > 20.f) ? v : log1pf(__expf(v));
                delta[((size_t)dir * MROWS + rbase + i * 16 + q * 4 + r) * DI + col] = sp;
            }
        }
}

// ---------------------------------------------------------------------------
// Depthwise causal conv (K=4) + bias + silu on xz (sum of 2 K-split planes),
// register-window version: thread owns (dir,b,d, 16-l tile).
__global__ __launch_bounds__(256) void k_conv(const float* __restrict__ xz,
                                              const float* __restrict__ cw,
                                              const float* __restrict__ cb,
                                              _Float16* __restrict__ xh,
                                              _Float16* __restrict__ xl) {
    const size_t S = (size_t)MROWS * F2D;
    int dir = blockIdx.z, b = blockIdx.y;
    int lchunk = blockIdx.x / 6, dsub = blockIdx.x % 6;
    int d = dsub * 256 + threadIdx.x;
    int base = lchunk * 16;

    const float* w = cw + ((size_t)dir * DI + d) * KI;
    float w0 = w[0], w1 = w[1], w2 = w[2], w3 = w[3];
    float bias = cb[(size_t)dir * DI + d];

    auto ld = [&](int m) -> float {
        if (m < 0) return 0.f;
        int src = perm_idx(dir, m);
        size_t o = ((size_t)b * 256 + src) * F2D + d;
        return xz[o] + xz[S + o];
    };
    float xm3 = ld(base - 3), xm2 = ld(base - 2), xm1 = ld(base - 1);

    #pragma unroll
    for (int j = 0; j < 16; ++j) {
        float cur = ld(base + j);
        float s = bias + w0 * xm3 + w1 * xm2 + w2 * xm1 + w3 * cur;
        xm3 = xm2; xm2 = xm1; xm1 = cur;
        float x = s / (1.f + __expf(-s));
        _Float16 h = (_Float16)x;
        size_t o = ((size_t)dir * MROWS + b * 256 + base + j) * DI + d;
        xh[o] = h;
        xl[o] = (_Float16)(x - (float)h);
    }
}

// ---------------------------------------------------------------------------
// Selective scan v5: two-phase structure (sY transpose write phase, stores
// OFF the dependent chain), no z (gating in k_sum), delta fp32.
// Block = 32 d x 8 n-pairs; double-buffered LDS; DPP 8-lane reduction.
// ---------------------------------------------------------------------------
__global__ __launch_bounds__(256) void k_scan(const float* __restrict__ delta,
                                              const _Float16* __restrict__ xhg,
                                              const _Float16* __restrict__ xlg,
                                              const float* __restrict__ BCm,
                                              const float* __restrict__ A_log,
                                              const float* __restrict__ Dp,
                                              float* __restrict__ ydir) {
    const int dchunk = blockIdx.x, b = blockIdx.y, dir = blockIdx.z;
    const int tid = threadIdx.x;
    const int dslot = tid >> 3;        // 0..31
    const int np = tid & 7;            // n-pair index
    const int d0 = dchunk * 32, d = d0 + dslot;

    __shared__ float sdx[2][32][64];   // [buf][jj][dslot*2 + {0:delta,1:x}]
    __shared__ float sbc[2][32][32];   // [buf][jj][n*2 + {0:B,1:C}]
    __shared__ float sY[32][32];

    const float Av0 = -__expf(A_log[((size_t)dir * DI + d) * NI + 2 * np]) * LOG2E;
    const float Av1 = -__expf(A_log[((size_t)dir * DI + d) * NI + 2 * np + 1]) * LOG2E;
    const float Dpar = Dp[(size_t)dir * DI + d];
    float h0 = 0.f, h1 = 0.f;

    const size_t dirrow = (size_t)dir * MROWS;
    const int srow = tid >> 3, sc4 = (tid & 7) * 4;   // staging roles

    floatx4 rdel, rbc;
    halfx4 rxh, rxl;
    auto load_chunk = [&](int j0) {
        int row = b * 256 + j0 + srow;
        size_t o = (dirrow + row) * DI + d0 + sc4;
        rdel = *(const floatx4*)(delta + o);
        rxh  = *(const halfx4*)(xhg + o);
        rxl  = *(const halfx4*)(xlg + o);
        rbc  = *(const floatx4*)(BCm + (dirrow + row) * 32 + sc4);
    };

    load_chunk(0);

    for (int c = 0; c < 8; ++c) {
        const int buf = c & 1;
        // stage chunk c
        #pragma unroll
        for (int e = 0; e < 4; ++e) {
            sdx[buf][srow][(sc4 + e) * 2]     = rdel[e];
            sdx[buf][srow][(sc4 + e) * 2 + 1] = (float)rxh[e] + (float)rxl[e];
        }
        *(floatx4*)&sbc[buf][srow][sc4] = rbc;
        __syncthreads();                       // chunk c visible; sY free
        if (c < 7) load_chunk((c + 1) * 32);   // prefetch, no wait

        // ---- 32 recurrence steps ----
        #pragma unroll
        for (int jj = 0; jj < 32; ++jj) {
            floatx2 dx = *(const floatx2*)&sdx[buf][jj][dslot * 2];
            floatx4 bc = *(const floatx4*)&sbc[buf][jj][np * 4];  // B0,C0,B1,C1
            float dv = dx[0], xv = dx[1];
            float a0 = __builtin_amdgcn_exp2f(dv * Av0);
            float a1 = __builtin_amdgcn_exp2f(dv * Av1);
            float du = dv * xv;
            h0 = fmaf(a0, h0, du * bc[0]);
            h1 = fmaf(a1, h1, du * bc[2]);
            float p = fmaf(h1, bc[3], h0 * bc[1]);
            p = grp8_sum(p);
            if (np == 0) sY[jj][dslot] = fmaf(Dpar, xv, p);
        }
        __syncthreads();                       // sY complete

        // ---- ungated write to out-domain (4 floats/thread, 128B rows) ----
        {
            int lout = perm_idx(dir, c * 32 + srow);
            floatx4 o = *(const floatx4*)&sY[srow][sc4];
            *(floatx4*)&ydir[(dirrow + (size_t)b * 256 + lout) * DI + d0 + sc4] = o;
        }
    }
}

// sum of 4 direction outputs, gate by silu(z) -> hi/lo fp16 for out_proj
__global__ __launch_bounds__(256) void k_sum(const float* __restrict__ ydir,
                                             const float* __restrict__ xz,
                                             _Float16* __restrict__ yh,
                                             _Float16* __restrict__ yl) {
    int i4 = (blockIdx.x * 256 + threadIdx.x) * 4;
    const size_t S = (size_t)MROWS * DI;
    const size_t SZ = (size_t)MROWS * F2D;
    int row = i4 / DI, dcol = i4 - row * DI;
    size_t zo = (size_t)row * F2D + DI + dcol;
    floatx4 zv = *(const floatx4*)(xz + zo) + *(const floatx4*)(xz + SZ + zo);
    floatx4 s = *(const floatx4*)(ydir + i4) + *(const floatx4*)(ydir + S + i4) +
                *(const floatx4*)(ydir + 2 * S + i4) + *(const floatx4*)(ydir + 3 * S + i4);
    halfx4 hh, hl;
    #pragma unroll
    for (int e = 0; e < 4; ++e) {
        float g = zv[e] / (1.f + __expf(-zv[e]));
        float v = s[e] * g;
        _Float16 h = (_Float16)v;
        hh[e] = h; hl[e] = (_Float16)(v - (float)h);
    }
    *(halfx4*)(yh + i4) = hh;
    *(halfx4*)(yl + i4) = hl;
}

// ---------------------------------------------------------------------------
extern "C" void kernel_launch(void* const* d_in, const int* in_sizes, int n_in,
                              void* d_out, int out_size, void* d_ws, size_t ws_size,
                              hipStream_t stream) {
    const float* hs   = (const float*)d_in[0];
    const float* wip  = (const float*)d_in[1];
    const float* wop  = (const float*)d_in[2];
    const float* cw   = (const float*)d_in[3];
    const float* cb   = (const float*)d_in[4];
    const float* xw   = (const float*)d_in[5];
    const float* dtw  = (const float*)d_in[6];
    const float* dtb  = (const float*)d_in[7];
    const float* alog = (const float*)d_in[8];
    const float* dpar = (const float*)d_in[9];
    float* out = (float*)d_out;

    char* p = (char*)d_ws;
    auto alloc_f32 = [&](size_t n) { float* r = (float*)p; p += n * 4; return r; };
    auto alloc_f16 = [&](size_t n) { _Float16* r = (_Float16*)p; p += n * 2; return r; };

    _Float16* hsh  = alloc_f16(786432);
    _Float16* hsl  = alloc_f16(786432);
    _Float16* wiph = alloc_f16(2359296);
    _Float16* wipl = alloc_f16(2359296);
    _Float16* woph = alloc_f16(1179648);
    _Float16* wopl = alloc_f16(1179648);
    _Float16* xwh  = alloc_f16(491520);
    _Float16* xwl  = alloc_f16(491520);
    _Float16* dtwh = alloc_f16((size_t)NDIRS * DI * 64);
    _Float16* dtwl = alloc_f16((size_t)NDIRS * DI * 64);
    float*    xz   = alloc_f32((size_t)2 * MROWS * F2D);   // two K-split planes
    _Float16* xh   = alloc_f16((size_t)NDIRS * MROWS * DI);
    _Float16* xl   = alloc_f16((size_t)NDIRS * MROWS * DI);
    _Float16* dtqh = alloc_f16((size_t)NDIRS * MROWS * 64);
    _Float16* dtql = alloc_f16((size_t)NDIRS * MROWS * 64);
    float*    BCm  = alloc_f32((size_t)NDIRS * MROWS * 32);
    float*    delta= alloc_f32((size_t)NDIRS * MROWS * DI);
    float*    ydir = alloc_f32((size_t)NDIRS * MROWS * DI);
    _Float16* yh   = alloc_f16((size_t)MROWS * DI);
    _Float16* yl   = alloc_f16((size_t)MROWS * DI);

    // aliases onto dead regions (disjoint lifetimes):
    float* xdba = ydir;    // xdbl 8 planes (10.5 MB <= 25.2 MB); dead after k_xsplit
    float* oacc = delta;   // outproj 4 planes (12.6 MB <= 25.2 MB); delta dead after scan

    k_splitall<<<dim3(5088), 256, 0, stream>>>(hs, wip, wop, xw, dtw,
                                               hsh, hsl, wiph, wipl, woph, wopl,
                                               xwh, xwl, dtwh, dtwl);
    k_inproj_t<<<dim3(8, 24, 2), 256, 0, stream>>>(hsh, hsl, wiph, wipl, xz);
    k_conv    <<<dim3(96, BI, NDIRS), 256, 0, stream>>>(xz, cw, cb, xh, xl);
    k_xdbl_t  <<<dim3(8, NDIRS, 8), 256, 0, stream>>>(xh, xl, xwh, xwl, xdba);
    k_xsplit  <<<dim3(1536), 256, 0, stream>>>(xdba, dtqh, dtql, BCm);
    k_delta_t <<<dim3(16, 12, NDIRS), 256, 0, stream>>>(dtqh, dtql, dtwh, dtwl, dtb, delta);
    k_scan    <<<dim3(DI / 32, BI, NDIRS), 256, 0, stream>>>(delta, xh, xl, BCm,
                                                             alog, dpar, ydir);
    k_sum     <<<dim3(1536), 256, 0, stream>>>(ydir, xz, yh, yl);
    k_outproj_t<<<dim3(16, 6, 4), 256, 0, stream>>>(yh, yl, woph, wopl, oacc);
    k_osum    <<<dim3(768), 256, 0, stream>>>(oacc, out);
}